// Round 1
// baseline (399.579 us; speedup 1.0000x reference)
//
#include <hip/hip_runtime.h>
#include <hip/hip_bf16.h>
#include <math.h>

typedef unsigned short ushort_t; // bf16 bits
typedef __attribute__((ext_vector_type(8))) short short8;
typedef __attribute__((ext_vector_type(8))) __bf16 bf16x8;
typedef __attribute__((ext_vector_type(4))) float f32x4;

#define SDIM 2048
#define EDIM 768
#define NTOK 4096

static __device__ __forceinline__ ushort_t f2bf(float f) {
  unsigned u = __builtin_bit_cast(unsigned, f);
  u += 0x7fff + ((u >> 16) & 1);
  return (ushort_t)(u >> 16);
}
static __device__ __forceinline__ float bf2f(ushort_t h) {
  return __builtin_bit_cast(float, (unsigned)h << 16);
}
static __device__ __forceinline__ f32x4 mfma16(short8 a, short8 b, f32x4 c) {
  return __builtin_amdgcn_mfma_f32_16x16x32_bf16(
      __builtin_bit_cast(bf16x8, a), __builtin_bit_cast(bf16x8, b), c, 0, 0, 0);
}
static __device__ __forceinline__ void gload_lds16(const void* g, void* l) {
  __builtin_amdgcn_global_load_lds(
      (const __attribute__((address_space(1))) void*)g,
      (__attribute__((address_space(3))) void*)l, 16, 0, 0);
}

// ---------- cast+transpose: out[C][R] bf16 = in[R][C]^T ----------
__global__ void k_castT(const float* __restrict__ in, ushort_t* __restrict__ out,
                        int R, int C) {
  __shared__ float tile[32][33];
  int c0 = blockIdx.x * 32, r0 = blockIdx.y * 32;
  int tx = threadIdx.x, ty = threadIdx.y;
#pragma unroll
  for (int i = 0; i < 32; i += 8)
    tile[ty + i][tx] = in[(size_t)(r0 + ty + i) * C + c0 + tx];
  __syncthreads();
#pragma unroll
  for (int i = 0; i < 32; i += 8)
    out[(size_t)(c0 + ty + i) * R + r0 + tx] = f2bf(tile[tx][ty + i]);
}

// ---------- w1 shifted copies: w1s[i][e][m] = w1[e][i+m] ----------
__global__ void k_w1shift(const float* __restrict__ w1, ushort_t* __restrict__ w1s) {
  int idx = blockIdx.x * 256 + threadIdx.x; // < 768*768
  int e = idx / 768, m = idx - (idx / 768) * 768;
#pragma unroll
  for (int i = 0; i < 4; i++)
    w1s[((size_t)i * 768 + e) * 768 + m] = f2bf(w1[(size_t)e * 3072 + i + m]);
}

// ---------- b1eff[n] = sum_m b1[i+m]*wvqc[m][j] + bvqc[j], n=j*4+i ----------
__global__ void k_b1eff(const float* __restrict__ b1, const float* __restrict__ wvqc,
                        const float* __restrict__ bvqc, float* __restrict__ b1e) {
  int n = blockIdx.x * 256 + threadIdx.x;
  if (n >= 3072) return;
  int i = n & 3, j = n >> 2;
  float s = bvqc[j];
  for (int m = 0; m < 768; m++) s += b1[i + m] * wvqc[(size_t)m * 768 + j];
  b1e[n] = s;
}

// ---------- LayerNorm row kernel: fp32 in -> bf16 out ----------
__global__ __launch_bounds__(256) void k_ln(const float* __restrict__ x,
                                            const float* __restrict__ gam,
                                            const float* __restrict__ bet,
                                            ushort_t* __restrict__ out) {
  const int row = blockIdx.x, t = threadIdx.x;
  const float* xr = x + (size_t)row * EDIM;
  float v0 = xr[t], v1 = xr[t + 256], v2 = xr[t + 512];
  float s = v0 + v1 + v2;
  float s2 = v0 * v0 + v1 * v1 + v2 * v2;
#pragma unroll
  for (int m = 32; m; m >>= 1) { s += __shfl_xor(s, m); s2 += __shfl_xor(s2, m); }
  __shared__ float red[8];
  const int wid = t >> 6, lane = t & 63;
  if (lane == 0) { red[wid] = s; red[4 + wid] = s2; }
  __syncthreads();
  s = red[0] + red[1] + red[2] + red[3];
  s2 = red[4] + red[5] + red[6] + red[7];
  float mean = s * (1.f / EDIM);
  float var = s2 * (1.f / EDIM) - mean * mean;
  float rstd = rsqrtf(var + 1e-5f);
  ushort_t* orow = out + (size_t)row * EDIM;
  orow[t] = f2bf((v0 - mean) * rstd * gam[t] + bet[t]);
  orow[t + 256] = f2bf((v1 - mean) * rstd * gam[t + 256] + bet[t + 256]);
  orow[t + 512] = f2bf((v2 - mean) * rstd * gam[t + 512] + bet[t + 512]);
}

// ---------- q row scale: rsqrt(64*max(sum q^2,1e-5)) ----------
__global__ __launch_bounds__(256) void k_qscale(const ushort_t* __restrict__ q,
                                                float* __restrict__ qs) {
  const int lane = threadIdx.x & 63, w = threadIdx.x >> 6;
  const int row = blockIdx.x * 4 + w;
  float v = bf2f(q[(size_t)row * 64 + lane]);
  float s = v * v;
#pragma unroll
  for (int m = 32; m; m >>= 1) s += __shfl_xor(s, m);
  if (lane == 0) qs[row] = rsqrtf(64.f * fmaxf(s, 1e-5f));
}

// ---------- GEMM: C[M,N] = A[M,K](bf16) * Bt[N,K]^T(bf16), modes: ----------
// 0: QKV scatter to [B,H,S,D] (+bias per third)    1: f32 out = resid + acc + bias
// 2: gelu(acc+bias) -> bf16                        3: W1effT store row*4+z
template <int MODE>
__global__ __launch_bounds__(256) void k_gemm(
    const ushort_t* __restrict__ A, const ushort_t* __restrict__ Bt, int K,
    const float* __restrict__ b0, const float* __restrict__ b1p,
    const float* __restrict__ b2p, float* __restrict__ outF,
    const float* __restrict__ resid, ushort_t* __restrict__ o0,
    ushort_t* __restrict__ o1, ushort_t* __restrict__ o2, int ldc) {
  __shared__ ushort_t As[128 * 32];
  __shared__ ushort_t Bs[128 * 32];
  const int t = threadIdx.x;
  const int m0 = blockIdx.x * 128, n0 = blockIdx.y * 128;
  if (MODE == 3) Bt += (size_t)blockIdx.z * 768 * 768;
  const int rowa = t >> 2, seg = t & 3;
  const ushort_t* ga = A + (size_t)(m0 + rowa) * K + seg * 8;
  const ushort_t* gb = Bt + (size_t)(n0 + rowa) * K + seg * 8;
  const int lbase = (t & ~63) * 8;
  const int lane = t & 63, wid = t >> 6;
  const int g = lane >> 4, c = lane & 15;
  const int wm = (wid >> 1) * 64, wn = (wid & 1) * 64;
  f32x4 acc[4][4] = {};
  for (int k0 = 0; k0 < K; k0 += 32) {
    gload_lds16(ga + k0, As + lbase);
    gload_lds16(ga + k0 + (size_t)64 * K, As + 2048 + lbase);
    gload_lds16(gb + k0, Bs + lbase);
    gload_lds16(gb + k0 + (size_t)64 * K, Bs + 2048 + lbase);
    __syncthreads();
    short8 af[4], bfr[4];
#pragma unroll
    for (int mt = 0; mt < 4; mt++)
      af[mt] = *(const short8*)(As + (wm + mt * 16 + c) * 32 + g * 8);
#pragma unroll
    for (int nt = 0; nt < 4; nt++)
      bfr[nt] = *(const short8*)(Bs + (wn + nt * 16 + c) * 32 + g * 8);
#pragma unroll
    for (int mt = 0; mt < 4; mt++)
#pragma unroll
      for (int nt = 0; nt < 4; nt++)
        acc[mt][nt] = mfma16(af[mt], bfr[nt], acc[mt][nt]);
    __syncthreads();
  }
#pragma unroll
  for (int mt = 0; mt < 4; mt++) {
#pragma unroll
    for (int nt = 0; nt < 4; nt++) {
#pragma unroll
      for (int r = 0; r < 4; r++) {
        int row = m0 + wm + mt * 16 + g * 4 + r;
        int col = n0 + wn + nt * 16 + c;
        float val = acc[mt][nt][r];
        if constexpr (MODE == 0) {
          int which = col / 768;
          int nn = col - which * 768;
          int h = nn >> 6, d = nn & 63;
          int bb = row >> 11, s = row & 2047;
          const float* bp = which == 0 ? b0 : (which == 1 ? b1p : b2p);
          ushort_t* dp = which == 0 ? o0 : (which == 1 ? o1 : o2);
          dp[(((size_t)(bb * 12 + h)) * SDIM + s) * 64 + d] = f2bf(val + bp[nn]);
        } else if constexpr (MODE == 1) {
          size_t o = (size_t)row * ldc + col;
          outF[o] = resid[o] + val + b0[col];
        } else if constexpr (MODE == 2) {
          float xg = val + b0[col];
          float ge = 0.5f * xg * (1.0f + erff(xg * 0.70710678118f));
          o0[(size_t)row * ldc + col] = f2bf(ge);
        } else {
          o0[((size_t)row * 4 + blockIdx.z) * ldc + col] = f2bf(val);
        }
      }
    }
  }
}

// ---------- flash attention: 1 wave per 16 q rows ----------
__global__ __launch_bounds__(64) void k_attn(const ushort_t* __restrict__ q,
                                             const ushort_t* __restrict__ k,
                                             const ushort_t* __restrict__ v,
                                             const float* __restrict__ qs,
                                             ushort_t* __restrict__ vals) {
  const int lane = threadIdx.x;
  const int g = lane >> 4, c = lane & 15;
  const int bh = blockIdx.y, q0 = blockIdx.x * 16;
  const int bb = bh / 12, h = bh - bb * 12;
  const ushort_t* qb = q + (size_t)bh * SDIM * 64;
  const ushort_t* kb = k + (size_t)bh * SDIM * 64;
  const ushort_t* vb = v + (size_t)bh * SDIM * 64;
  short8 aq0 = *(const short8*)(qb + (q0 + c) * 64 + g * 8);
  short8 aq1 = *(const short8*)(qb + (q0 + c) * 64 + 32 + g * 8);
  float sc[4], mrun[4], lrun[4];
  f32x4 accO[4] = {};
#pragma unroll
  for (int r = 0; r < 4; r++) {
    sc[r] = qs[bh * SDIM + q0 + g * 4 + r];
    mrun[r] = -INFINITY;
    lrun[r] = 0.f;
  }
  __shared__ ushort_t Pl[16 * 32];
  for (int t0 = 0; t0 < SDIM; t0 += 32) {
    const ushort_t* kt = kb + (size_t)t0 * 64;
    short8 b00 = *(const short8*)(kt + c * 64 + g * 8);
    short8 b01 = *(const short8*)(kt + c * 64 + 32 + g * 8);
    short8 b10 = *(const short8*)(kt + (16 + c) * 64 + g * 8);
    short8 b11 = *(const short8*)(kt + (16 + c) * 64 + 32 + g * 8);
    f32x4 s0 = {}, s1 = {};
    s0 = mfma16(aq0, b00, s0);
    s0 = mfma16(aq1, b01, s0);
    s1 = mfma16(aq0, b10, s1);
    s1 = mfma16(aq1, b11, s1);
#pragma unroll
    for (int r = 0; r < 4; r++) {
      float l0 = s0[r] * sc[r], l1 = s1[r] * sc[r];
      float mx = fmaxf(l0, l1);
      mx = fmaxf(mx, __shfl_xor(mx, 1));
      mx = fmaxf(mx, __shfl_xor(mx, 2));
      mx = fmaxf(mx, __shfl_xor(mx, 4));
      mx = fmaxf(mx, __shfl_xor(mx, 8));
      float mn = fmaxf(mrun[r], mx);
      float alpha = __expf(mrun[r] - mn);
      float p0 = __expf(l0 - mn), p1 = __expf(l1 - mn);
      float ps = p0 + p1;
      ps += __shfl_xor(ps, 1);
      ps += __shfl_xor(ps, 2);
      ps += __shfl_xor(ps, 4);
      ps += __shfl_xor(ps, 8);
      lrun[r] = lrun[r] * alpha + ps;
      mrun[r] = mn;
#pragma unroll
      for (int dt = 0; dt < 4; dt++) accO[dt][r] *= alpha;
      Pl[(g * 4 + r) * 32 + c] = f2bf(p0);
      Pl[(g * 4 + r) * 32 + 16 + c] = f2bf(p1);
    }
    __syncthreads();
    short8 pa = *(const short8*)(Pl + c * 32 + g * 8);
    __syncthreads();
    const ushort_t* vt = vb + (size_t)t0 * 64;
#pragma unroll
    for (int dt = 0; dt < 4; dt++) {
      short8 vf;
#pragma unroll
      for (int j = 0; j < 8; j++) vf[j] = (short)vt[(g * 8 + j) * 64 + dt * 16 + c];
      accO[dt] = mfma16(pa, vf, accO[dt]);
    }
  }
#pragma unroll
  for (int dt = 0; dt < 4; dt++)
#pragma unroll
    for (int r = 0; r < 4; r++) {
      int s = q0 + g * 4 + r;
      float val = accO[dt][r] / lrun[r];
      vals[((size_t)(bb * SDIM + s)) * EDIM + h * 64 + dt * 16 + c] = f2bf(val);
    }
}

extern "C" void kernel_launch(void* const* d_in, const int* in_sizes, int n_in,
                              void* d_out, int out_size, void* d_ws, size_t ws_size,
                              hipStream_t stream) {
  const float* x = (const float*)d_in[0];
  const float* ln1g = (const float*)d_in[1];
  const float* ln1b = (const float*)d_in[2];
  const float* wq = (const float*)d_in[3];
  const float* bq = (const float*)d_in[4];
  const float* wk = (const float*)d_in[5];
  const float* bk = (const float*)d_in[6];
  const float* wv = (const float*)d_in[7];
  const float* bv = (const float*)d_in[8];
  const float* wo = (const float*)d_in[9];
  const float* bo = (const float*)d_in[10];
  const float* ln2g = (const float*)d_in[11];
  const float* ln2b = (const float*)d_in[12];
  const float* w1 = (const float*)d_in[13];
  const float* b1 = (const float*)d_in[14];
  const float* wvqc = (const float*)d_in[15];
  const float* bvqc = (const float*)d_in[16];
  const float* w2 = (const float*)d_in[17];
  const float* b2 = (const float*)d_in[18];
  float* out = (float*)d_out;

  char* w = (char*)d_ws;
  ushort_t* xn = (ushort_t*)(w + 0);           // 6291456
  ushort_t* xn2 = (ushort_t*)(w + 6291456);    // 6291456
  float* x2 = (float*)(w + 12582912);          // 12582912
  ushort_t* qb = (ushort_t*)(w + 25165824);    // 6291456
  ushort_t* kb = (ushort_t*)(w + 31457280);    // 6291456
  ushort_t* vb = (ushort_t*)(w + 37748736);    // 6291456
  ushort_t* vals = (ushort_t*)(w + 44040192);  // 6291456
  ushort_t* G = (ushort_t*)(w + 25165824);     // overlays q..vals (25165824)
  float* qsc = (float*)(w + 50331648);         // 196608
  ushort_t* wqkvT = (ushort_t*)(w + 50528256); // 3538944
  ushort_t* woT = (ushort_t*)(w + 54067200);   // 1179648
  ushort_t* wvqcT = (ushort_t*)(w + 55246848); // 1179648
  ushort_t* w1s = (ushort_t*)(w + 56426496);   // 4718592
  ushort_t* W1eT = (ushort_t*)(w + 61145088);  // 4718592
  float* b1e = (float*)(w + 65863680);         // 12288
  ushort_t* w2T = (ushort_t*)(w + 65875968);   // 4718592 -> end 70594560

  dim3 tb(32, 8);
  k_castT<<<dim3(24, 24), tb, 0, stream>>>(wq, wqkvT, 768, 768);
  k_castT<<<dim3(24, 24), tb, 0, stream>>>(wk, wqkvT + 768 * 768, 768, 768);
  k_castT<<<dim3(24, 24), tb, 0, stream>>>(wv, wqkvT + 2 * 768 * 768, 768, 768);
  k_castT<<<dim3(24, 24), tb, 0, stream>>>(wo, woT, 768, 768);
  k_castT<<<dim3(24, 24), tb, 0, stream>>>(wvqc, wvqcT, 768, 768);
  k_castT<<<dim3(24, 96), tb, 0, stream>>>(w2, w2T, 3072, 768);
  k_w1shift<<<2304, 256, 0, stream>>>(w1, w1s);
  k_b1eff<<<12, 256, 0, stream>>>(b1, wvqc, bvqc, b1e);
  // W1effT[j*4+i][e] = sum_m wvqcT[j][m] * w1s[i][e][m]
  k_gemm<3><<<dim3(6, 6, 4), 256, 0, stream>>>(wvqcT, w1s, 768, nullptr, nullptr,
                                               nullptr, nullptr, nullptr, W1eT,
                                               nullptr, nullptr, 768);
  k_ln<<<4096, 256, 0, stream>>>(x, ln1g, ln1b, xn);
  k_gemm<0><<<dim3(32, 18), 256, 0, stream>>>(xn, wqkvT, 768, bq, bk, bv, nullptr,
                                              nullptr, qb, kb, vb, 0);
  k_qscale<<<12288, 256, 0, stream>>>(qb, qsc);
  k_attn<<<dim3(128, 24), 64, 0, stream>>>(qb, kb, vb, qsc, vals);
  k_gemm<1><<<dim3(32, 6), 256, 0, stream>>>(vals, woT, 768, bo, nullptr, nullptr,
                                             x2, x, nullptr, nullptr, nullptr, 768);
  k_ln<<<4096, 256, 0, stream>>>(x2, ln2g, ln2b, xn2);
  k_gemm<2><<<dim3(32, 24), 256, 0, stream>>>(xn2, W1eT, 768, b1e, nullptr, nullptr,
                                              nullptr, nullptr, G, nullptr, nullptr,
                                              3072);
  k_gemm<1><<<dim3(32, 6), 256, 0, stream>>>(G, w2T, 3072, b2, nullptr, nullptr,
                                             out, x2, nullptr, nullptr, nullptr, 768);
}